// Round 7
// baseline (435.893 us; speedup 1.0000x reference)
//
#include <hip/hip_runtime.h>
#include <hip/hip_bf16.h>

// DensePermutation: P21 = softmax_j(-||feat2_i - feat1_j|| / 0.1)
// feat1, feat2: [8192][128] f32.  out: [8192][8192] f32.
//
//  K0: split f32 -> bf16 hi/lo planes (Markidis) + row sq-norms.
//  K1: strip-mined MFMA pass -> per-(row, jb) online-softmax partials (m,l).
//  K2: reduce 8 partials/row -> row max, 1/rowsum.
//  K3: strip-mined MFMA pass again, fused epilogue writes P (the 256MB traffic).
//
// Block = 128 rows x 1024 cols (8 j-tiles of 128), 512 threads (8 waves 2x4).
// A panel (f2, hi+lo, 64KB) staged ONCE per block; B tile (f1, 64KB) staged per
// j-tile with issue-early/write-late (T14) reg staging. jb = bid&7 pins one
// B-strip (512KB) per XCD L2 under round-robin dispatch.
// NOTE: sqrtf, NOT __sqrtf — glibc declares __sqrtf host-only; 3 device calls
// to it were the R5 compile failure.

#define N 8192
#define NJT 8

typedef short s16x8 __attribute__((ext_vector_type(8)));
typedef unsigned short u16x8 __attribute__((ext_vector_type(8)));
typedef float f32x4 __attribute__((ext_vector_type(4)));

// ws layout (bytes)
#define OFF_F1H (0u)
#define OFF_F1L (2u << 20)
#define OFF_F2H (4u << 20)
#define OFF_F2L (6u << 20)
#define OFF_SQ1 (8u << 20)
#define OFF_SQ2 ((8u << 20) + (32u << 10))
#define OFF_MX  ((8u << 20) + (64u << 10))
#define OFF_RL  ((8u << 20) + (96u << 10))
#define OFF_PM  ((8u << 20) + (128u << 10))   // [8192][8] f32 = 256KB
#define OFF_PL  ((10u << 20) + (128u << 10))  // [8192][8] f32

// LDS layout (dynamic, 140800 B total)
#define L_A    0
#define L_B    65536
#define L_SQ1  131072   // [1024] f32
#define L_SQ2  135168   // [128] f32
#define L_MX   135680   // [128] f32
#define L_RL   136192   // [128] f32
#define L_PMW  136704   // [128][4] f32
#define L_PLW  138752   // [128][4] f32
#define LDS_BYTES 140800

__device__ inline unsigned short f2bf(float x) {
    unsigned u = __builtin_bit_cast(unsigned, x);
    return (unsigned short)((u + 0x7fffu + ((u >> 16) & 1u)) >> 16);
}
__device__ inline float bf2f(unsigned short b) {
    return __builtin_bit_cast(float, (unsigned)b << 16);
}

// ---------------- K0: split + row norms ----------------
__global__ __launch_bounds__(256) void k_split(
        const float* __restrict__ f1, const float* __restrict__ f2,
        unsigned short* __restrict__ f1h, unsigned short* __restrict__ f1l,
        unsigned short* __restrict__ f2h, unsigned short* __restrict__ f2l,
        float* __restrict__ sq1, float* __restrict__ sq2) {
    const int wid = threadIdx.x >> 6, lane = threadIdx.x & 63;
    const int row = blockIdx.x * 4 + wid;
    const float* src = blockIdx.y ? f2 : f1;
    unsigned short* dh = blockIdx.y ? f2h : f1h;
    unsigned short* dl = blockIdx.y ? f2l : f1l;
    float* sq = blockIdx.y ? sq2 : sq1;

    float2 x = ((const float2*)src)[row * 64 + lane];
    unsigned short h0 = f2bf(x.x), h1 = f2bf(x.y);
    unsigned short l0 = f2bf(x.x - bf2f(h0)), l1 = f2bf(x.y - bf2f(h1));
    ((ushort2*)dh)[row * 64 + lane] = make_ushort2(h0, h1);
    ((ushort2*)dl)[row * 64 + lane] = make_ushort2(l0, l1);
    float s = x.x * x.x + x.y * x.y;
    #pragma unroll
    for (int m = 32; m; m >>= 1) s += __shfl_xor(s, m);
    if (lane == 0) sq[row] = s;
}

// ---------------- K1/K3: strip-mined MFMA core ----------------
template <int PASS>
__global__ __launch_bounds__(512, 2) void k_gemm2(
        const unsigned short* __restrict__ f1h, const unsigned short* __restrict__ f1l,
        const unsigned short* __restrict__ f2h, const unsigned short* __restrict__ f2l,
        const float* __restrict__ sq1, const float* __restrict__ sq2,
        const float* __restrict__ mx, const float* __restrict__ rlv,
        float* __restrict__ pm, float* __restrict__ pl,
        float* __restrict__ out) {
    extern __shared__ char lds[];
    const int t = threadIdx.x;
    const int bid = blockIdx.x;
    const int it = bid >> 3, jb = bid & 7;   // jb = XCD id under round-robin
    const int i0 = it * 128, jbase = jb * 1024;
    const int w = t >> 6, lane = t & 63;
    const int wr = w >> 2, wc = w & 3;       // wave tile: 64 rows x 32 cols
    const int lr = lane & 15, kg = lane >> 4;

    float* sq1s = (float*)(lds + L_SQ1);
    float* sq2t = (float*)(lds + L_SQ2);
    float* mxt  = (float*)(lds + L_MX);
    float* rlt  = (float*)(lds + L_RL);
    float* pmw  = (float*)(lds + L_PMW);
    float* plw  = (float*)(lds + L_PLW);

    // ---- prologue: stage A panel (once) + B tile 0 + tables ----
    u16x8 bpay[8];
    {
        u16x8 apay[8];
        #pragma unroll
        for (int q = 0; q < 8; ++q) {
            int p = q >> 2, rem = (q & 3) * 512 + t, r = rem >> 4, cc = rem & 15;
            apay[q] = *(const u16x8*)((p ? f2l : f2h) + (i0 + r) * 128 + cc * 8);
            bpay[q] = *(const u16x8*)((p ? f1l : f1h) + (jbase + r) * 128 + cc * 8);
        }
        #pragma unroll
        for (int q = 0; q < 8; ++q) {
            int p = q >> 2, rem = (q & 3) * 512 + t, r = rem >> 4, cc = rem & 15;
            int loff = p * 32768 + r * 256 + ((cc ^ (r & 7)) << 4);
            *(u16x8*)(lds + L_A + loff) = apay[q];
            *(u16x8*)(lds + L_B + loff) = bpay[q];
        }
        sq1s[t] = sq1[jbase + t];
        sq1s[512 + t] = sq1[jbase + 512 + t];
        if (t < 128) {
            sq2t[t] = sq2[i0 + t];
            if (PASS == 2) { mxt[t] = mx[i0 + t]; rlt[t] = rlv[i0 + t]; }
        }
    }
    __syncthreads();

    float rm[4][4], rs[4][4];
    #pragma unroll
    for (int a = 0; a < 4; ++a)
        #pragma unroll
        for (int b = 0; b < 4; ++b) { rm[a][b] = -1e30f; rs[a][b] = 0.0f; }

    for (int jt = 0; jt < NJT; ++jt) {
        // T14 issue-early: prefetch next B tile into regs (lands under compute)
        if (jt < NJT - 1) {
            int j0n = jbase + (jt + 1) * 128;
            #pragma unroll
            for (int q = 0; q < 8; ++q) {
                int p = q >> 2, rem = (q & 3) * 512 + t, r = rem >> 4, cc = rem & 15;
                bpay[q] = *(const u16x8*)((p ? f1l : f1h) + (j0n + r) * 128 + cc * 8);
            }
        }

        f32x4 acc[4][2];
        #pragma unroll
        for (int a = 0; a < 4; ++a)
            #pragma unroll
            for (int b = 0; b < 2; ++b) acc[a][b] = (f32x4){0.f, 0.f, 0.f, 0.f};

        #pragma unroll
        for (int kc = 0; kc < 4; ++kc) {
            s16x8 ah[4], al[4];
            #pragma unroll
            for (int mi = 0; mi < 4; ++mi) {
                int row = wr * 64 + mi * 16 + lr;
                int off = row * 256 + ((((kc * 4 + kg)) ^ (row & 7)) << 4);
                ah[mi] = *(const s16x8*)(lds + L_A + off);
                al[mi] = *(const s16x8*)(lds + L_A + 32768 + off);
            }
            #pragma unroll
            for (int ni = 0; ni < 2; ++ni) {
                int col = wc * 32 + ni * 16 + lr;
                int off = col * 256 + ((((kc * 4 + kg)) ^ (col & 7)) << 4);
                s16x8 bh = *(const s16x8*)(lds + L_B + off);
                s16x8 bl_ = *(const s16x8*)(lds + L_B + 32768 + off);
                #pragma unroll
                for (int mi = 0; mi < 4; ++mi) {
                    acc[mi][ni] = __builtin_amdgcn_mfma_f32_16x16x32_bf16(ah[mi], bh, acc[mi][ni], 0, 0, 0);
                    acc[mi][ni] = __builtin_amdgcn_mfma_f32_16x16x32_bf16(ah[mi], bl_, acc[mi][ni], 0, 0, 0);
                    acc[mi][ni] = __builtin_amdgcn_mfma_f32_16x16x32_bf16(al[mi], bh, acc[mi][ni], 0, 0, 0);
                }
            }
        }

        if (PASS == 2) {
            #pragma unroll
            for (int mi = 0; mi < 4; ++mi)
                #pragma unroll
                for (int rg = 0; rg < 4; ++rg) {
                    int row_l = wr * 64 + mi * 16 + kg * 4 + rg;
                    float s2 = sq2t[row_l], m_ = mxt[row_l], r_ = rlt[row_l];
                    #pragma unroll
                    for (int ni = 0; ni < 2; ++ni) {
                        int ct = jt * 128 + wc * 32 + ni * 16 + lr;
                        float sd = s2 + sq1s[ct] - 2.0f * acc[mi][ni][rg];
                        float pv = __expf(-10.0f * sqrtf(fmaxf(sd, 0.0f)) - m_) * r_;
                        out[(i0 + row_l) * N + jbase + ct] = pv;
                    }
                }
        } else {
            #pragma unroll
            for (int mi = 0; mi < 4; ++mi)
                #pragma unroll
                for (int rg = 0; rg < 4; ++rg) {
                    int row_l = wr * 64 + mi * 16 + kg * 4 + rg;
                    float s2 = sq2t[row_l];
                    float lv0 = -10.0f * sqrtf(fmaxf(s2 + sq1s[jt * 128 + wc * 32 + lr] - 2.0f * acc[mi][0][rg], 0.0f));
                    float lv1 = -10.0f * sqrtf(fmaxf(s2 + sq1s[jt * 128 + wc * 32 + 16 + lr] - 2.0f * acc[mi][1][rg], 0.0f));
                    float tm = fmaxf(lv0, lv1);
                    if (tm > rm[mi][rg]) {
                        rs[mi][rg] *= __expf(rm[mi][rg] - tm);
                        rm[mi][rg] = tm;
                    }
                    rs[mi][rg] += __expf(lv0 - rm[mi][rg]) + __expf(lv1 - rm[mi][rg]);
                }
        }

        __syncthreads();   // all waves done reading B tile jt
        if (jt < NJT - 1) {
            #pragma unroll
            for (int q = 0; q < 8; ++q) {
                int p = q >> 2, rem = (q & 3) * 512 + t, r = rem >> 4, cc = rem & 15;
                *(u16x8*)(lds + L_B + p * 32768 + r * 256 + ((cc ^ (r & 7)) << 4)) = bpay[q];
            }
        }
        __syncthreads();   // B tile jt+1 visible
    }

    if (PASS == 1) {
        #pragma unroll
        for (int mi = 0; mi < 4; ++mi)
            #pragma unroll
            for (int rg = 0; rg < 4; ++rg) {
                float m_ = rm[mi][rg], s_ = rs[mi][rg];
                #pragma unroll
                for (int msk = 1; msk < 16; msk <<= 1) {
                    float om = __shfl_xor(m_, msk);
                    float os = __shfl_xor(s_, msk);
                    float nm = fmaxf(m_, om);
                    s_ = s_ * __expf(m_ - nm) + os * __expf(om - nm);
                    m_ = nm;
                }
                if (lr == 0) {
                    int row_l = wr * 64 + mi * 16 + kg * 4 + rg;
                    pmw[row_l * 4 + wc] = m_;
                    plw[row_l * 4 + wc] = s_;
                }
            }
        __syncthreads();
        if (t < 128) {
            float m_ = pmw[t * 4], s_ = plw[t * 4];
            #pragma unroll
            for (int p = 1; p < 4; ++p) {
                float om = pmw[t * 4 + p], os = plw[t * 4 + p];
                float nm = fmaxf(m_, om);
                s_ = s_ * __expf(m_ - nm) + os * __expf(om - nm);
                m_ = nm;
            }
            pm[(i0 + t) * 8 + jb] = m_;
            pl[(i0 + t) * 8 + jb] = s_;
        }
    }
}

// ---------------- K2: reduce 8 partials per row ----------------
__global__ __launch_bounds__(256) void k_reduce2(
        const float* __restrict__ pm, const float* __restrict__ pl,
        float* __restrict__ mx, float* __restrict__ rlv) {
    const int row = blockIdx.x * 256 + threadIdx.x;
    float m = pm[row * 8];
    #pragma unroll
    for (int p = 1; p < 8; ++p) m = fmaxf(m, pm[row * 8 + p]);
    float s = 0.0f;
    #pragma unroll
    for (int p = 0; p < 8; ++p) s += pl[row * 8 + p] * __expf(pm[row * 8 + p] - m);
    mx[row] = m;
    rlv[row] = 1.0f / s;
}

extern "C" void kernel_launch(void* const* d_in, const int* in_sizes, int n_in,
                              void* d_out, int out_size, void* d_ws, size_t ws_size,
                              hipStream_t stream) {
    const float* f1 = (const float*)d_in[0];
    const float* f2 = (const float*)d_in[1];
    float* out = (float*)d_out;
    char* ws = (char*)d_ws;

    unsigned short* f1h = (unsigned short*)(ws + OFF_F1H);
    unsigned short* f1l = (unsigned short*)(ws + OFF_F1L);
    unsigned short* f2h = (unsigned short*)(ws + OFF_F2H);
    unsigned short* f2l = (unsigned short*)(ws + OFF_F2L);
    float* sq1 = (float*)(ws + OFF_SQ1);
    float* sq2 = (float*)(ws + OFF_SQ2);
    float* mx  = (float*)(ws + OFF_MX);
    float* rlv = (float*)(ws + OFF_RL);
    float* pm  = (float*)(ws + OFF_PM);
    float* pl  = (float*)(ws + OFF_PL);

    (void)hipFuncSetAttribute(reinterpret_cast<const void*>(&k_gemm2<1>),
                              hipFuncAttributeMaxDynamicSharedMemorySize, LDS_BYTES);
    (void)hipFuncSetAttribute(reinterpret_cast<const void*>(&k_gemm2<2>),
                              hipFuncAttributeMaxDynamicSharedMemorySize, LDS_BYTES);

    k_split<<<dim3(N / 4, 2), 256, 0, stream>>>(f1, f2, f1h, f1l, f2h, f2l, sq1, sq2);
    k_gemm2<1><<<512, 512, LDS_BYTES, stream>>>(f1h, f1l, f2h, f2l, sq1, sq2, mx, rlv, pm, pl, out);
    k_reduce2<<<N / 256, 256, 0, stream>>>(pm, pl, mx, rlv);
    k_gemm2<2><<<512, 512, LDS_BYTES, stream>>>(f1h, f1l, f2h, f2l, sq1, sq2, mx, rlv, pm, pl, out);
}